// Round 14
// baseline (711.429 us; speedup 1.0000x reference)
//
#include <hip/hip_runtime.h>
#include <hip/hip_bf16.h>
#include <math.h>

#define BATCH 128
#define TT    12
#define CIN   10
#define HID   64
#define PLANE 625
#define NU    10          // 16B channel-units per pixel (80 padded ch)
#define IPB   50000       // shorts per batch image in inp: NU*PLANE*8
#define NKB   45          // k-blocks: 9 taps * 5 chunks of 16 ch
#define NKB_ALLOC (NKB+6)
#define CSZ   (BATCH*PLANE*HID)   // floats in c buffer
#define KSPLIT 10         // k_mlp1 k splits

typedef __attribute__((ext_vector_type(8)))  short bf16x8;
typedef __attribute__((ext_vector_type(16))) float f32x16;

__device__ __forceinline__ float fsigm(float v){ return 1.f/(1.f+__expf(-v)); }
__device__ __forceinline__ float ftanh(float v){ return 1.f - 2.f/(__expf(2.f*v)+1.f); }
__device__ __forceinline__ unsigned short f2bf(float v){
    __hip_bfloat16 b = __float2bfloat16(v);
    return *reinterpret_cast<unsigned short*>(&b);
}

// ---- prepack conv_w (256,74,3,3) f32 -> B-fragments bf16 ----
// k = tap*80 + ch, n-permutation: col = jlo*4 + g  (j = nt*8+jlo, o = g*64+j)
// frag layout (32x32x16 B): lane l: col = l&31, k_local = (l>>5)*8 + e
__global__ void k_wprep(const float* __restrict__ w, unsigned short* __restrict__ wpk){
    int tid = blockIdx.x*256 + threadIdx.x;      // NKB*8*64 = 23040 total
    if (tid >= NKB*8*64) return;
    int lane = tid & 63;
    int nt   = (tid >> 6) & 7;
    int kb   = tid >> 9;
    int tap = kb/5, ci = kb - tap*5;
    int ky = tap/3, kx = tap - ky*3;
    int g = lane & 3, jlo = (lane & 31) >> 2, kh = lane >> 5;
    int o = g*64 + nt*8 + jlo;
    union { unsigned short u[8]; float4 f; } pk;
    #pragma unroll
    for (int e = 0; e < 8; ++e){
        int ch = ci*16 + kh*8 + e;
        float v = (ch < 74) ? w[((o*74 + ch)*3 + ky)*3 + kx] : 0.f;
        pk.u[e] = f2bf(v);
    }
    *reinterpret_cast<float4*>(wpk + (size_t)tid*8) = pk.f;   // idx = (kb*8+nt)*64+lane
}

// ---- transpose w1 -> w1t rows k' = m*64+j ----
__global__ void k_w1prep(const float* __restrict__ w1, float* __restrict__ w1t){
    int tid = blockIdx.x*256 + threadIdx.x;
    if (tid >= 40000*4) return;
    int rowp = tid >> 2, f4 = tid & 3;
    int m = rowp >> 6, j = rowp & 63;
    const float4* src = (const float4*)(w1 + (size_t)(j*625 + m)*16);
    ((float4*)(w1t + (size_t)rowp*16))[f4] = src[f4];
}

// ---- copy x_0 into inp buffer x-slots (unit-major bf16 layout) ----
__global__ void k_xcopy(const float* __restrict__ x, unsigned short* __restrict__ inp, int t){
    int idx = blockIdx.x*256 + threadIdx.x;
    if (idx >= BATCH*CIN*PLANE) return;
    int m  = idx % PLANE;
    int r  = idx / PLANE;
    int ch = r % CIN;
    int b  = r / CIN;
    float v = x[((size_t)(b*TT + t)*CIN + ch)*PLANE + m];
    inp[(size_t)b*IPB + ((((ch>>3)*PLANE) + m)<<3) + (ch&7)] = f2bf(v);
}

// per-kb A offset in shorts: tap-walk + ci*(2 units of 216 pix * 8 shorts)
__device__ constexpr int TOFF[9] = {0,8,16,216,224,232,432,440,448};
#define AOFF(kb) (TOFF[(kb)/5] + ((kb)%5)*3456)

// ---- fused conv-as-GEMM (MFMA bf16) + LSTM pointwise + next-step x-copy ----
// 128m x 256n blocks, grid (5 mg, 128 b) = 640 blocks, 8 waves = 4 nt-pairs x 2 mt-pairs;
// wave = 2nt x 2mt (4 acc). B staged per-kb into LDS (one global_load_lds per wave),
// double-buffered at 2-kb phases (23 barriers) -> B L2 traffic halved (471->236 MB,
// round-13 post-mortem: per-wave B streams from L2 were the binding resource).
// K-loop fully unrolled: every ds_read offset is a compile-time immediate, zero VALU.
__global__ __launch_bounds__(512) void k_gemm(
    const float* __restrict__ x,
    const unsigned short* __restrict__ inp,   // step-t input, unit-major
    unsigned short* __restrict__ inpn,        // next-step buffer
    const unsigned short* __restrict__ wpk,
    const float* __restrict__ bias,           // conv_b[256], o = g*64+j
    float* __restrict__ cbuf,                 // [b][625][64] fp32
    unsigned short* __restrict__ hbf,         // [b][m*64+j] relu'd bf16 h (t=TT-1)
    int t)
{
    __shared__ __align__(16) unsigned short at2[2160*8];   // [10 u][8r*27c][8], 34.56 KB
    __shared__ __align__(16) unsigned short wls[2][8192];  // 2 bufs x 2 kb x 8 frags, 32 KB

    const int tid  = threadIdx.x;
    const int mg   = blockIdx.x;              // 0..4 (128 m each; m 625..639 pad)
    const int b    = blockIdx.y;
    const int lane = tid & 63;
    const int w    = tid >> 6;                // wave id
    const int ntp  = w & 3;                   // n-tile pair (covers nt = 2*ntp, 2*ntp+1)
    const int mtp  = w >> 2;                  // m-tile pair (covers mt = 2*mtp, 2*mtp+1)
    const int r0row = (mg*128)/25;            // 0,5,10,15,20

    // ---- stage A-tile: rows r0row-1..r0row+6, cols -1..25, zero halo/pad ----
    const unsigned short* ib = inp + (size_t)b*IPB;
    for (int idx = tid; idx < 2160; idx += 512){
        int q   = idx/216, pix = idx - q*216;
        int rr  = pix/27,  cc  = pix - rr*27;
        int gr  = r0row - 1 + rr, gc = cc - 1;
        float4 v = {0.f,0.f,0.f,0.f};
        if ((unsigned)gr < 25u && (unsigned)gc < 25u)
            v = *reinterpret_cast<const float4*>(ib + (((size_t)q*PLANE + gr*25 + gc)<<3));
        *reinterpret_cast<float4*>(at2 + ((size_t)idx<<3)) = v;
    }

    // per-lane A bases for the wave's 2 m-tiles (rebased so all tap offsets >= 0)
    const int kh = lane >> 5;
    const unsigned short *a0, *a1;
    {
        int m0 = mg*128 + (mtp*2+0)*32 + (lane & 31);
        int r_ = m0/25, c_ = m0 - r_*25;
        a0 = at2 + kh*1728 + (((r_ - r0row + 1)*27 + c_ - 27) << 3);
        int m1 = mg*128 + (mtp*2+1)*32 + (lane & 31);
        r_ = m1/25; c_ = m1 - r_*25;
        a1 = at2 + kh*1728 + (((r_ - r0row + 1)*27 + c_ - 27) << 3);
    }
    // B read base: this wave's first frag slot (nt = 2*ntp), lane's 16B
    const unsigned short* bb = &wls[0][0] + ntp*1024 + lane*8;

    // B stage: wave w stages frag (kb, nt=w): 64 lanes x 16B = 1 KB
    auto stageB = [&](int kb, int bufsel, int slot){
        __builtin_amdgcn_global_load_lds(
            (const __attribute__((address_space(1))) void*)(wpk + ((size_t)(kb*8 + w))*512 + lane*8),
            (__attribute__((address_space(3))) void*)(&wls[bufsel][slot*4096 + w*512]),
            16, 0, 0);
    };

    f32x16 acc00, acc01, acc10, acc11;        // [mt][nt]
    #pragma unroll
    for (int e = 0; e < 16; ++e){ acc00[e]=0.f; acc01[e]=0.f; acc10[e]=0.f; acc11[e]=0.f; }

    // prologue: stage kb 0,1 into buf0 (drained by first barrier)
    stageB(0, 0, 0);
    stageB(1, 0, 1);

    #define KBSTEP(kb, buf, q) { \
        bf16x8 b0 = *reinterpret_cast<const bf16x8*>(bb + (buf)*8192 + (q)*4096); \
        bf16x8 b1 = *reinterpret_cast<const bf16x8*>(bb + (buf)*8192 + (q)*4096 + 512); \
        bf16x8 f0 = *reinterpret_cast<const bf16x8*>(a0 + AOFF(kb)); \
        bf16x8 f1 = *reinterpret_cast<const bf16x8*>(a1 + AOFF(kb)); \
        acc00 = __builtin_amdgcn_mfma_f32_32x32x16_bf16(f0, b0, acc00, 0,0,0); \
        acc10 = __builtin_amdgcn_mfma_f32_32x32x16_bf16(f1, b0, acc10, 0,0,0); \
        acc01 = __builtin_amdgcn_mfma_f32_32x32x16_bf16(f0, b1, acc01, 0,0,0); \
        acc11 = __builtin_amdgcn_mfma_f32_32x32x16_bf16(f1, b1, acc11, 0,0,0); \
    }

    #pragma unroll
    for (int p = 0; p < 23; ++p){
        __syncthreads();                       // wls[p&1] ready for all waves
        if (p < 21){                           // stage kb 2p+2, 2p+3 into other buf
            stageB(2*p+2, (p+1)&1, 0);
            stageB(2*p+3, (p+1)&1, 1);
        } else if (p == 21){
            stageB(44, 0, 0);                  // last kb -> buf0 slot0 (phase 22)
        }
        KBSTEP(2*p, p&1, 0);
        if (2*p+1 < NKB) KBSTEP(2*p+1, p&1, 1);
    }
    #undef KBSTEP

    // ---- fused LSTM epilogue: quad transpose -> all lanes update ----
    const int g   = lane & 3;
    const int jlo = (lane & 31) >> 2;
    const int j0  = (ntp*2+0)*8 + jlo;
    const int j1  = (ntp*2+1)*8 + jlo;
    const float bown0 = bias[g*64 + j0];
    const float bown1 = bias[g*64 + j1];
    const float sA = (g == 3) ? 2.f : 1.f;    // act = sA*sigm(sA*x) + sB (tanh when g=3)
    const float sB = (g == 3) ? -1.f : 0.f;
    const int  mbase = mg*128 + mtp*64 + 4*kh;
    const bool gb0 = (g & 1), gb1 = (g & 2);
    float* cb = cbuf + (size_t)b*PLANE*HID;
    unsigned short* hn  = inpn + (size_t)b*IPB;
    unsigned short* hfb = hbf  + (size_t)b*40000;

    #pragma unroll
    for (int mt_ = 0; mt_ < 2; ++mt_){
        #pragma unroll
        for (int n = 0; n < 2; ++n){
            const f32x16& A = (mt_ == 0) ? (n == 0 ? acc00 : acc01)
                                         : (n == 0 ? acc10 : acc11);
            const int   jj = n ? j1 : j0;
            const float bw = n ? bown1 : bown0;
            const int  chh = CIN + jj, uh = chh >> 3, sh = chh & 7;
            #pragma unroll
            for (int rq = 0; rq < 4; ++rq){
                float v0 = fmaf(sA, fsigm(sA*(A[rq*4+0] + bw)), sB);
                float v1 = fmaf(sA, fsigm(sA*(A[rq*4+1] + bw)), sB);
                float v2 = fmaf(sA, fsigm(sA*(A[rq*4+2] + bw)), sB);
                float v3 = fmaf(sA, fsigm(sA*(A[rq*4+3] + bw)), sB);
                float s;
                s = __shfl_xor(gb0 ? v0 : v1, 1); if (gb0) v0 = s; else v1 = s;
                s = __shfl_xor(gb0 ? v2 : v3, 1); if (gb0) v2 = s; else v3 = s;
                s = __shfl_xor(gb1 ? v0 : v2, 2); if (gb1) v0 = s; else v2 = s;
                s = __shfl_xor(gb1 ? v1 : v3, 2); if (gb1) v1 = s; else v3 = s;
                // v0=i, v1=f, v2=o, v3=g~ of element m
                const int m = mbase + mt_*32 + g + 8*rq;
                if (m < PLANE){
                    float co = cb[m*HID + jj];
                    float cn = fmaf(v1, co, v0*v3);
                    float h  = v2 * ftanh(cn);
                    if (t < TT-1){
                        cb[m*HID + jj] = cn;
                        hn[((uh*PLANE + m) << 3) + sh] = f2bf(h);
                    } else {
                        hfb[m*64 + jj] = f2bf(h > 0.f ? h : 0.f);
                    }
                }
            }
        }
    }

    // ---- fused x-copy for step t+1 (this block's 128-m slice) ----
    if (t < TT-1){
        const float* xn = x + (size_t)(b*TT + t + 1)*CIN*PLANE;
        for (int idx = tid; idx < 1280; idx += 512){
            int ch = idx >> 7, mi = idx & 127;
            int m = mg*128 + mi;
            if (m < PLANE)
                inpn[(size_t)b*IPB + ((((ch>>3)*PLANE) + m)<<3) + (ch&7)] =
                    f2bf(xn[ch*PLANE + m]);
        }
    }
}

// -------- MLP stage 1: partial h@w1, coalesced bf16 h + transposed w1 --------
__global__ __launch_bounds__(256) void k_mlp1(
    const unsigned short* __restrict__ hbf, const float* __restrict__ w1t,
    float* __restrict__ part)
{
    __shared__ float xw[4][4][16];
    const int ks = blockIdx.x, bg = blockIdx.y, tid = threadIdx.x;
    const int kw0 = ks*4000, kw1 = kw0 + 4000;
    const unsigned short* h0 = hbf + (size_t)(bg*4+0)*40000;
    const unsigned short* h1 = hbf + (size_t)(bg*4+1)*40000;
    const unsigned short* h2 = hbf + (size_t)(bg*4+2)*40000;
    const unsigned short* h3 = hbf + (size_t)(bg*4+3)*40000;

    float acc[4][16];
    #pragma unroll
    for (int bi = 0; bi < 4; ++bi)
        #pragma unroll
        for (int n = 0; n < 16; ++n) acc[bi][n] = 0.f;

    for (int kw = kw0 + tid*2; kw < kw1; kw += 512){
        const float4* wp = (const float4*)(w1t + (size_t)kw*16);
        float4 q0 = wp[0], q1 = wp[1], q2 = wp[2], q3 = wp[3];
        float4 r0 = wp[4], r1 = wp[5], r2 = wp[6], r3 = wp[7];
        unsigned int u0 = *(const unsigned int*)(h0 + kw);
        unsigned int u1 = *(const unsigned int*)(h1 + kw);
        unsigned int u2 = *(const unsigned int*)(h2 + kw);
        unsigned int u3 = *(const unsigned int*)(h3 + kw);
        #define ACC1(bi, u) { \
            float fl = __uint_as_float((u) << 16); \
            float fh = __uint_as_float((u) & 0xffff0000u); \
            acc[bi][ 0]=fmaf(fl,q0.x,fmaf(fh,r0.x,acc[bi][ 0])); \
            acc[bi][ 1]=fmaf(fl,q0.y,fmaf(fh,r0.y,acc[bi][ 1])); \
            acc[bi][ 2]=fmaf(fl,q0.z,fmaf(fh,r0.z,acc[bi][ 2])); \
            acc[bi][ 3]=fmaf(fl,q0.w,fmaf(fh,r0.w,acc[bi][ 3])); \
            acc[bi][ 4]=fmaf(fl,q1.x,fmaf(fh,r1.x,acc[bi][ 4])); \
            acc[bi][ 5]=fmaf(fl,q1.y,fmaf(fh,r1.y,acc[bi][ 5])); \
            acc[bi][ 6]=fmaf(fl,q1.z,fmaf(fh,r1.z,acc[bi][ 6])); \
            acc[bi][ 7]=fmaf(fl,q1.w,fmaf(fh,r1.w,acc[bi][ 7])); \
            acc[bi][ 8]=fmaf(fl,q2.x,fmaf(fh,r2.x,acc[bi][ 8])); \
            acc[bi][ 9]=fmaf(fl,q2.y,fmaf(fh,r2.y,acc[bi][ 9])); \
            acc[bi][10]=fmaf(fl,q2.z,fmaf(fh,r2.z,acc[bi][10])); \
            acc[bi][11]=fmaf(fl,q2.w,fmaf(fh,r2.w,acc[bi][11])); \
            acc[bi][12]=fmaf(fl,q3.x,fmaf(fh,r3.x,acc[bi][12])); \
            acc[bi][13]=fmaf(fl,q3.y,fmaf(fh,r3.y,acc[bi][13])); \
            acc[bi][14]=fmaf(fl,q3.z,fmaf(fh,r3.z,acc[bi][14])); \
            acc[bi][15]=fmaf(fl,q3.w,fmaf(fh,r3.w,acc[bi][15])); }
        ACC1(0, u0) ACC1(1, u1) ACC1(2, u2) ACC1(3, u3)
        #undef ACC1
    }

    #pragma unroll
    for (int d = 1; d < 64; d <<= 1)
        #pragma unroll
        for (int bi = 0; bi < 4; ++bi)
            #pragma unroll
            for (int n = 0; n < 16; ++n) acc[bi][n] += __shfl_xor(acc[bi][n], d);
    if ((tid & 63) == 0){
        int w = tid >> 6;
        #pragma unroll
        for (int bi = 0; bi < 4; ++bi)
            #pragma unroll
            for (int n = 0; n < 16; ++n) xw[w][bi][n] = acc[bi][n];
    }
    __syncthreads();
    if (tid < 64){
        int bi = tid >> 4, n = tid & 15;
        float s = xw[0][bi][n] + xw[1][bi][n] + xw[2][bi][n] + xw[3][bi][n];
        part[((size_t)(bg*4 + bi)*KSPLIT + ks)*16 + n] = s;
    }
}

// -------- MLP stage 2: fold partials, 16 -> 8 -> 2 -> log_softmax --------
__global__ __launch_bounds__(128) void k_mlp2(
    const float* __restrict__ part,
    const float* __restrict__ b1,
    const float* __restrict__ w2, const float* __restrict__ b2,
    const float* __restrict__ w3, const float* __restrict__ b3,
    float* __restrict__ out)
{
    const int b = threadIdx.x;
    float h1[16];
    #pragma unroll
    for (int i = 0; i < 16; ++i) h1[i] = b1[i];
    for (int s = 0; s < KSPLIT; ++s)
        #pragma unroll
        for (int i = 0; i < 16; ++i) h1[i] += part[((size_t)b * KSPLIT + s) * 16 + i];
    #pragma unroll
    for (int i = 0; i < 16; ++i) h1[i] = h1[i] > 0.f ? h1[i] : 0.f;

    float h2[8];
    #pragma unroll
    for (int i = 0; i < 8; ++i){
        float s2 = b2[i];
        #pragma unroll
        for (int k2 = 0; k2 < 16; ++k2) s2 += h1[k2] * w2[k2*8 + i];
        h2[i] = s2 > 0.f ? s2 : 0.f;
    }
    float l0 = b3[0], l1 = b3[1];
    #pragma unroll
    for (int k3 = 0; k3 < 8; ++k3){ l0 += h2[k3]*w3[k3*2]; l1 += h2[k3]*w3[k3*2+1]; }
    float m   = fmaxf(l0, l1);
    float lse = m + logf(__expf(l0 - m) + __expf(l1 - m));
    out[b*2 + 0] = l0 - lse;
    out[b*2 + 1] = l1 - lse;
}

extern "C" void kernel_launch(void* const* d_in, const int* in_sizes, int n_in,
                              void* d_out, int out_size, void* d_ws, size_t ws_size,
                              hipStream_t stream) {
    const float* x      = (const float*)d_in[0];
    const float* conv_w = (const float*)d_in[1];
    const float* conv_b = (const float*)d_in[2];
    const float* w1     = (const float*)d_in[3];
    const float* b1     = (const float*)d_in[4];
    const float* w2     = (const float*)d_in[5];
    const float* b2     = (const float*)d_in[6];
    const float* w3     = (const float*)d_in[7];
    const float* b3     = (const float*)d_in[8];
    float* out = (float*)d_out;

    unsigned short* inp0 = (unsigned short*)d_ws;
    unsigned short* inp1 = inp0 + (size_t)BATCH*IPB;
    float* c   = (float*)(inp1 + (size_t)BATCH*IPB);
    unsigned short* hbf = (unsigned short*)(c + CSZ);
    unsigned short* wpk = hbf + (size_t)BATCH*40000;
    float* w1t  = (float*)(wpk + (size_t)NKB_ALLOC*8*64*8);
    float* part = w1t + 640000;

    // ws poisoned 0xAA, not re-poisoned between replays -> re-init every call
    hipMemsetAsync(inp0, 0, (size_t)BATCH*IPB*2, stream);   // zeros h(t=0) + ch pad
    hipMemsetAsync(inp1, 0, (size_t)BATCH*IPB*2, stream);   // zeros ch pad
    hipMemsetAsync(c,    0, (size_t)CSZ*4,       stream);

    k_wprep <<<dim3(90),   dim3(256), 0, stream>>>(conv_w, wpk);
    k_w1prep<<<dim3(625),  dim3(256), 0, stream>>>(w1, w1t);
    k_xcopy <<<dim3(3125), dim3(256), 0, stream>>>(x, inp0, 0);

    for (int t = 0; t < TT; ++t){
        unsigned short* ic  = (t & 1) ? inp1 : inp0;
        unsigned short* in_ = (t & 1) ? inp0 : inp1;
        k_gemm<<<dim3(5, BATCH), dim3(512), 0, stream>>>(x, ic, in_, wpk, conv_b, c, hbf, t);
    }
    k_mlp1<<<dim3(KSPLIT, 32), dim3(256), 0, stream>>>(hbf, w1t, part);
    k_mlp2<<<dim3(1), dim3(128), 0, stream>>>(part, b1, w2, b2, w3, b3, out);
}